// Round 7
// baseline (395.167 us; speedup 1.0000x reference)
//
#include <hip/hip_runtime.h>
#include <hip/hip_cooperative_groups.h>

namespace cg = cooperative_groups;

#define LN_EPS 1e-5f
#define D 128
#define SCAN_CHUNK 1024
#define LDSA_STRIDE 264   // bf16 units: 256 + 8 pad; row stride 528B (16B-aligned)

typedef __attribute__((ext_vector_type(4))) float f32x4;
typedef __attribute__((ext_vector_type(8))) short bf16x8;

static __device__ __forceinline__ ushort f2bf(float f) {
    union { float f; unsigned u; } a; a.f = f;
    unsigned r = a.u + 0x7FFF + ((a.u >> 16) & 1);   // RNE
    return (ushort)(r >> 16);
}
static __device__ __forceinline__ float bf2f(ushort u) {
    union { unsigned u; float f; } a; a.u = ((unsigned)u) << 16;
    return a.f;
}

// K0: blocks [0,128): pack B = [Wl^T ; Wr^T] into MFMA B-fragment order
// (lane L of frag (ks,jb) holds B[k=ks*32+(L>>4)*8+i][j=jb*16+(L&15)]);
// blocks [128,...): zero the degree histogram (absorbs the memset dispatch).
__global__ void prep_w(const float* __restrict__ Wl,
                       const float* __restrict__ Wr,
                       ushort* __restrict__ Bfrag,
                       int* __restrict__ hist, int N) {
    int idx = blockIdx.x * blockDim.x + threadIdx.x;
    if (blockIdx.x < 128) {
        int t = idx;                     // 0..32767
        int i    = t & 7;
        int lane = (t >> 3) & 63;
        int jb   = (t >> 9) & 7;
        int ks   = t >> 12;
        int k = ks * 32 + (lane >> 4) * 8 + i;
        int j = jb * 16 + (lane & 15);
        float v = (k < D) ? Wl[j * D + k] : Wr[j * D + (k - D)];
        Bfrag[t] = f2bf(v);
    } else {
        int i = idx - 128 * 256;
        if (i < N) hist[i] = 0;
    }
}

// K1 (merged): blocks [0, lnBlocks): LayerNorm+ReLU+mask -> bf16 h.
// 2 nodes per wave: 32 lanes x float4 = 512B coalesced row read, 5-step
// shuffle reduction (xor masks <32 stay within the 32-lane group).
// Blocks [lnBlocks,...): dst-degree histogram (one thread per edge).
__global__ void ln_hist(const float* __restrict__ x,
                        const float* __restrict__ mask,
                        const float* __restrict__ gamma,
                        const float* __restrict__ beta,
                        ushort* __restrict__ hbf,
                        const int* __restrict__ ei,
                        int* __restrict__ hist,
                        int N, int E, int lnBlocks) {
    if (blockIdx.x >= (unsigned)lnBlocks) {
        int e = (blockIdx.x - lnBlocks) * blockDim.x + threadIdx.x;
        if (e < E) atomicAdd(&hist[ei[E + e]], 1);
        return;
    }
    int idx  = blockIdx.x * blockDim.x + threadIdx.x;
    int node = idx >> 5;                 // 8 nodes per 256-thread block
    int sl   = threadIdx.x & 31;
    if (node >= N) return;
    float4 v = ((const float4*)(x + (size_t)node * D))[sl];
    float s  = v.x + v.y + v.z + v.w;
    float ss = fmaf(v.x, v.x, fmaf(v.y, v.y, fmaf(v.z, v.z, v.w * v.w)));
#pragma unroll
    for (int off = 16; off > 0; off >>= 1) {
        s  += __shfl_xor(s, off);
        ss += __shfl_xor(ss, off);
    }
    float mu  = s * (1.0f / D);
    float var = ss * (1.0f / D) - mu * mu;
    float rs  = rsqrtf(var + LN_EPS);
    float4 g = ((const float4*)gamma)[sl];
    float4 b = ((const float4*)beta)[sl];
    float4 m = ((const float4*)(mask + (size_t)node * D))[sl];
    ushort4 o;
    o.x = f2bf(fmaxf((v.x - mu) * rs * g.x + b.x, 0.0f) * m.x);
    o.y = f2bf(fmaxf((v.y - mu) * rs * g.y + b.y, 0.0f) * m.y);
    o.z = f2bf(fmaxf((v.z - mu) * rs * g.z + b.z, 0.0f) * m.z);
    o.w = f2bf(fmaxf((v.w - mu) * rs * g.w + b.w, 0.0f) * m.w);
    ((ushort4*)(hbf + (size_t)node * D))[sl] = o;
}

// K2 (cooperative): chunk scans -> grid.sync -> apply csums prefix + cursor
// init -> grid.sync -> counting-sort placement. 256 blocks, all co-resident.
__global__ void scan_sort(const int* __restrict__ ei,
                          const int* __restrict__ hist,
                          int* __restrict__ offs,
                          int* __restrict__ cursor,
                          int* __restrict__ csums,
                          int* __restrict__ ssrc,
                          int N, int E, int chunks) {
    cg::grid_group grid = cg::this_grid();
    __shared__ int lds[256];
    __shared__ int pref[128];
    int t = threadIdx.x;

    // Phase B1: per-chunk exclusive scan (chunks <= gridDim.x).
    if (blockIdx.x < (unsigned)chunks) {
        int base = blockIdx.x * SCAN_CHUNK;
        int idx0 = base + t * 4;
        int v[4];
#pragma unroll
        for (int i = 0; i < 4; i++) {
            int idx = idx0 + i;
            v[i] = (idx < N) ? hist[idx] : 0;
        }
        lds[t] = v[0] + v[1] + v[2] + v[3];
        __syncthreads();
        for (int off = 1; off < 256; off <<= 1) {
            int add = (t >= off) ? lds[t - off] : 0;
            __syncthreads();
            lds[t] += add;
            __syncthreads();
        }
        int run = (t == 0) ? 0 : lds[t - 1];
        if (t == 255) csums[blockIdx.x] = lds[255];
#pragma unroll
        for (int i = 0; i < 4; i++) {
            int idx = idx0 + i;
            if (idx < N) offs[idx] = run;
            run += v[i];
        }
    }
    __threadfence();
    grid.sync();

    // Phase B2: inclusive scan of csums in LDS, then offs += base, cursor=offs.
    if (t < 128) pref[t] = (t < chunks) ? csums[t] : 0;
    __syncthreads();
    for (int off = 1; off < 128; off <<= 1) {
        int add = (t < 128 && t >= off) ? pref[t - off] : 0;
        __syncthreads();
        if (t < 128) pref[t] += add;
        __syncthreads();
    }
    for (int i0 = blockIdx.x * 256; i0 < N; i0 += gridDim.x * 256) {
        int i = i0 + t;
        if (i < N) {
            int c = i >> 10;
            int b = c ? pref[c - 1] : 0;
            int v = offs[i] + b;
            offs[i] = v;
            cursor[i] = v;
        }
    }
    __threadfence();
    grid.sync();

    // Phase C: bucket edges by dst.
    int nth = gridDim.x * blockDim.x;
    for (int e = blockIdx.x * blockDim.x + t; e < E; e += nth) {
        int dst = ei[E + e];
        int pos = atomicAdd(&cursor[dst], 1);
        ssrc[pos] = ei[e];
    }
}

// K3: segmented mean-aggregate, 4 nodes per wave (16 lanes x bf16x8 = one
// 256B row read per node). Edge loop unrolled x2.
__global__ void aggregate4(const ushort* __restrict__ hbf,
                           const int* __restrict__ sorted_src,
                           const int* __restrict__ offs,
                           const int* __restrict__ hist,
                           ushort* __restrict__ magg, int N) {
    int wid  = (blockIdx.x * blockDim.x + threadIdx.x) >> 6;
    int lane = threadIdx.x & 63;
    int g  = lane >> 4;
    int sl = lane & 15;
    int node = wid * 4 + g;
    bool valid = node < N;
    int start = 0, deg = 0;
    if (valid) { start = offs[node]; deg = hist[node]; }
    float acc[8];
#pragma unroll
    for (int j = 0; j < 8; j++) acc[j] = 0.0f;
    int i = 0;
    for (; i + 2 <= deg; i += 2) {
        int s0 = sorted_src[start + i];
        int s1 = sorted_src[start + i + 1];
        bf16x8 v0 = *(const bf16x8*)(hbf + (size_t)s0 * D + sl * 8);
        bf16x8 v1 = *(const bf16x8*)(hbf + (size_t)s1 * D + sl * 8);
#pragma unroll
        for (int j = 0; j < 8; j++)
            acc[j] += bf2f((ushort)v0[j]) + bf2f((ushort)v1[j]);
    }
    if (i < deg) {
        int s0 = sorted_src[start + i];
        bf16x8 v0 = *(const bf16x8*)(hbf + (size_t)s0 * D + sl * 8);
#pragma unroll
        for (int j = 0; j < 8; j++) acc[j] += bf2f((ushort)v0[j]);
    }
    if (valid) {
        float inv = 1.0f / fmaxf((float)deg, 1.0f);
        bf16x8 o;
#pragma unroll
        for (int j = 0; j < 8; j++) o[j] = (short)f2bf(acc[j] * inv);
        *(bf16x8*)(magg + (size_t)node * D + sl * 8) = o;
    }
}

// K4: out = [magg | h] @ B + bias via bf16 MFMA.
__global__ void __launch_bounds__(256, 3)
out_gemm_mfma(float* __restrict__ out,
              const ushort* __restrict__ magg,
              const ushort* __restrict__ hbf,
              const ushort* __restrict__ Bfrag,
              const float* __restrict__ bl,
              int N) {
    __shared__ ushort Alds[64 * LDSA_STRIDE];
    int tid  = threadIdx.x;
    int wave = tid >> 6;
    int lane = tid & 63;
    int n0 = blockIdx.x * 64;

    bf16x8 breg[8][2];
#pragma unroll
    for (int ks = 0; ks < 8; ks++)
#pragma unroll
        for (int jj = 0; jj < 2; jj++) {
            int jb = wave * 2 + jj;
            breg[ks][jj] = *(const bf16x8*)(Bfrag + (size_t)((ks * 8 + jb) * 64 + lane) * 8);
        }

#pragma unroll
    for (int it = 0; it < 4; it++) {
        int chunk = tid + 256 * it;
        int row = chunk >> 4;
        int c8  = chunk & 15;
        int node = n0 + row;
        bf16x8 va = (bf16x8){0,0,0,0,0,0,0,0};
        bf16x8 vh = (bf16x8){0,0,0,0,0,0,0,0};
        if (node < N) {
            va = *(const bf16x8*)(magg + (size_t)node * D + c8 * 8);
            vh = *(const bf16x8*)(hbf  + (size_t)node * D + c8 * 8);
        }
        *(bf16x8*)&Alds[row * LDSA_STRIDE + c8 * 8]       = va;
        *(bf16x8*)&Alds[row * LDSA_STRIDE + 128 + c8 * 8] = vh;
    }
    __syncthreads();

    f32x4 acc[4][2];
#pragma unroll
    for (int nb = 0; nb < 4; nb++)
#pragma unroll
        for (int jj = 0; jj < 2; jj++)
            acc[nb][jj] = (f32x4){0.f, 0.f, 0.f, 0.f};

    int arow = lane & 15;
    int akoff = (lane >> 4) * 8;
#pragma unroll
    for (int ks = 0; ks < 8; ks++) {
#pragma unroll
        for (int nb = 0; nb < 4; nb++) {
            bf16x8 a = *(const bf16x8*)&Alds[(nb * 16 + arow) * LDSA_STRIDE + ks * 32 + akoff];
            acc[nb][0] = __builtin_amdgcn_mfma_f32_16x16x32_bf16(a, breg[ks][0], acc[nb][0], 0, 0, 0);
            acc[nb][1] = __builtin_amdgcn_mfma_f32_16x16x32_bf16(a, breg[ks][1], acc[nb][1], 0, 0, 0);
        }
    }

    float bias0 = bl[wave * 32 + (lane & 15)];
    float bias1 = bl[wave * 32 + 16 + (lane & 15)];
    int rbase = (lane >> 4) * 4;
#pragma unroll
    for (int nb = 0; nb < 4; nb++) {
#pragma unroll
        for (int r = 0; r < 4; r++) {
            int row = nb * 16 + rbase + r;
            if (n0 + row < N) {
                float* orow = out + (size_t)(n0 + row) * D + wave * 32 + (lane & 15);
                orow[0]  = acc[nb][0][r] + bias0;
                orow[16] = acc[nb][1][r] + bias1;
            }
        }
    }
}

extern "C" void kernel_launch(void* const* d_in, const int* in_sizes, int n_in,
                              void* d_out, int out_size, void* d_ws, size_t ws_size,
                              hipStream_t stream) {
    const float* x     = (const float*)d_in[0];
    const int*   ei    = (const int*)  d_in[1];
    const float* mask  = (const float*)d_in[2];
    const float* gamma = (const float*)d_in[3];
    const float* beta  = (const float*)d_in[4];
    const float* Wl    = (const float*)d_in[5];
    const float* bl    = (const float*)d_in[6];
    const float* Wr    = (const float*)d_in[7];
    float* out = (float*)d_out;

    int N = in_sizes[0] / D;   // 100000
    int E = in_sizes[1] / 2;   // 600000
    int chunks = (N + SCAN_CHUNK - 1) / SCAN_CHUNK;  // 98

    // ws layout: hbf[N*D] us | magg[N*D] us | Bfrag[32768] us | hist[N]
    //            | offs[N] | cursor[N] | chunk_sums[128] | sorted_src[E]
    ushort* hbf   = (ushort*)d_ws;
    ushort* magg  = hbf + (size_t)N * D;
    ushort* Bfrag = magg + (size_t)N * D;
    int* hist   = (int*)(Bfrag + 32768);
    int* offs   = hist + N;
    int* cursor = offs + N;
    int* csums  = cursor + N;
    int* ssrc   = csums + 128;

    int lnBlocks   = (N + 7) / 8;            // 12500
    int histBlocks = (E + 255) / 256;        // 2344

    prep_w<<<128 + (N + 255) / 256, 256, 0, stream>>>(Wl, Wr, Bfrag, hist, N);
    ln_hist<<<lnBlocks + histBlocks, 256, 0, stream>>>(x, mask, gamma, beta, hbf,
                                                       ei, hist, N, E, lnBlocks);
    {
        void* args[] = {(void*)&ei, (void*)&hist, (void*)&offs, (void*)&cursor,
                        (void*)&csums, (void*)&ssrc, (void*)&N, (void*)&E,
                        (void*)&chunks};
        hipLaunchCooperativeKernel((void*)scan_sort, dim3(256), dim3(256),
                                   args, 0, stream);
    }
    aggregate4<<<((N + 3) / 4 + 3) / 4, 256, 0, stream>>>(hbf, ssrc, offs, hist, magg, N);
    out_gemm_mfma<<<(N + 63) / 64, 256, 0, stream>>>(out, magg, hbf, Bfrag, bl, N);
}